// Round 6
// baseline (879.867 us; speedup 1.0000x reference)
//
#include <hip/hip_runtime.h>

// Full MHA: x->QKV proj (bf16 MFMA GEMM) -> flash attention -> out proj.
// bf16 compute, fp32 accumulate.
// R6: flatmm GEMM with BK=64 K-loop, manually unrolled x2 with alternating
//     B-register sets (wfE/wfO): one barrier per 64-K (32 total), 32 MFMA/wave
//     per drain interval, zero register-rotation v_movs. A-only LDS dbuf
//     (2 x 16KB). R5 (BK=32) was 344us @ MfmaUtil 26%, VALU 32% - barrier
//     drains still exposed, rotation copies burned VALU.

typedef __bf16 bf16;
typedef __bf16 bf16x4 __attribute__((ext_vector_type(4)));
typedef __bf16 bf16x8 __attribute__((ext_vector_type(8)));
typedef float  f32x4  __attribute__((ext_vector_type(4)));

#define S_TOK 2048
#define DMODEL 2048
#define NHEAD 16
#define HDIM 128
#define BH_STRIDE ((size_t)S_TOK * HDIM)   // 262144 elems per (b,h)
#define KT32 (DMODEL / 32)                 // 64 32-k tiles per K
#define TILE_ELEMS 4096                    // 128n x 32k fragment-linear tile

__device__ __forceinline__ void load_lds16(const void* g, void* l) {
  __builtin_amdgcn_global_load_lds((const __attribute__((address_space(1))) void*)g,
                                   (__attribute__((address_space(3))) void*)l,
                                   16, 0, 0);
}

// ---------------- prep kernels ----------------

__global__ __launch_bounds__(256) void cvt_f32_bf16(const float* __restrict__ src,
                                                    bf16* __restrict__ dst) {
  size_t i = (size_t)blockIdx.x * 256 + threadIdx.x;
  float4 v = ((const float4*)src)[i];
  bf16x4 o;
  o[0] = (bf16)v.x; o[1] = (bf16)v.y; o[2] = (bf16)v.z; o[3] = (bf16)v.w;
  ((bf16x4*)dst)[i] = o;
}

// Pack W fp32 [K=2048][N=2048] row-major into fragment-linear bf16 tiles:
// dst[(nt*64 + kt)*4096 + i_g*512 + quad*128 + l16*8 + e]
//   = (bf16) W[kt*32 + quad*8 + e][nt*128 + i_g*16 + l16]
__global__ __launch_bounds__(256) void pack_w(const float* __restrict__ W,
                                              bf16* __restrict__ dst) {
  __shared__ bf16 lds[32 * 128];
  const int t = threadIdx.x;
  const int kt = blockIdx.x, nt = blockIdx.y;
  const int k0 = kt * 32, n0 = nt * 128;
#pragma unroll
  for (int p = 0; p < 4; ++p) {
    int kl = (t >> 5) + p * 8;
    int nl = (t & 31) * 4;
    float4 v = *(const float4*)(W + (size_t)(k0 + kl) * DMODEL + n0 + nl);
    lds[kl * 128 + nl + 0] = (bf16)v.x;
    lds[kl * 128 + nl + 1] = (bf16)v.y;
    lds[kl * 128 + nl + 2] = (bf16)v.z;
    lds[kl * 128 + nl + 3] = (bf16)v.w;
  }
  __syncthreads();
  bf16* out = dst + ((size_t)nt * KT32 + kt) * TILE_ELEMS;
#pragma unroll
  for (int u = 0; u < 2; ++u) {
    int c = t * 2 + u;
    int i_g = c >> 6, quad = (c >> 4) & 3, l16 = c & 15;
    bf16x8 v;
#pragma unroll
    for (int e = 0; e < 8; ++e)
      v[e] = lds[(quad * 8 + e) * 128 + i_g * 16 + l16];
    *(bf16x8*)(out + (size_t)c * 8) = v;
  }
}

// V reshuffle: vb[bh][s][d] -> vc[bh][s>>3][d][s&7]
__global__ __launch_bounds__(256) void v_chunk(const bf16* __restrict__ vb,
                                               bf16* __restrict__ vc) {
  __shared__ alignas(16) bf16 t[64 * 128];
  const int tid = threadIdx.x;
  const int s0 = blockIdx.x * 64;
  const size_t bhoff = (size_t)blockIdx.y * BH_STRIDE;
  const bf16* src = vb + bhoff + (size_t)s0 * HDIM;
#pragma unroll
  for (int r = 0; r < 4; ++r) {
    int c = r * 256 + tid;
    *(bf16x8*)(t + (size_t)c * 8) = *(const bf16x8*)(src + (size_t)(c >> 4) * HDIM + (c & 15) * 8);
  }
  __syncthreads();
  bf16* dst = vc + bhoff + (size_t)(s0 >> 3) * (HDIM * 8);
#pragma unroll
  for (int r = 0; r < 4; ++r) {
    int c = r * 256 + tid;
    int scl = c >> 7, d = c & 127;
    bf16x8 v;
#pragma unroll
    for (int e = 0; e < 8; ++e) v[e] = t[(size_t)(scl * 8 + e) * HDIM + d];
    *(bf16x8*)(dst + (size_t)scl * (HDIM * 8) + d * 8) = v;
  }
}

// ---------------- GEMM core: flatmm, BK=64, unroll x2 ----------------
// A -> LDS dbuf (2 x 16KB), staged 16KB per BK-iter via 4 global_load_lds.
// B -> fragment-linear panel, direct global->VGPR, alternating wfE/wfO sets.
// LDS A layout per buffer: chunk = kb(0..7)*128 + row; holds A[m0+row][kt*64+kb*8..+8].

#define GEMM_STAGE_A(buf, ktt)                                              \
  do {                                                                      \
    const bf16* _src = aptr + (ktt) * 64;                                   \
    load_lds16(_src,      (buf) + tid * 8);                                 \
    load_lds16(_src + 16, (buf) + (256 + tid) * 8);                         \
    load_lds16(_src + 32, (buf) + (512 + tid) * 8);                         \
    load_lds16(_src + 48, (buf) + (768 + tid) * 8);                         \
  } while (0)

#define GEMM_LOAD_B(wf, ktt)                                                \
  do {                                                                      \
    const bf16* _t0 = wb + (size_t)(2 * (ktt)) * TILE_ELEMS;                \
    _Pragma("unroll")                                                       \
    for (int j = 0; j < 4; ++j) {                                           \
      (wf)[j]     = *(const bf16x8*)(_t0 + (size_t)j * 512);                \
      (wf)[4 + j] = *(const bf16x8*)(_t0 + TILE_ELEMS + (size_t)j * 512);   \
    }                                                                       \
  } while (0)

#define GEMM_COMPUTE(buf, wf)                                               \
  do {                                                                      \
    _Pragma("unroll")                                                       \
    for (int s = 0; s < 2; ++s) {                                           \
      bf16x8 xf[4];                                                         \
      _Pragma("unroll")                                                     \
      for (int i = 0; i < 4; ++i)                                           \
        xf[i] = *(const bf16x8*)((buf) +                                    \
                 ((size_t)((4 * s + quad) * 128 + rw + i * 16 + l16)) * 8); \
      _Pragma("unroll")                                                     \
      for (int i = 0; i < 4; ++i)                                           \
        _Pragma("unroll")                                                   \
        for (int j = 0; j < 4; ++j)                                         \
          acc[i][j] = __builtin_amdgcn_mfma_f32_16x16x32_bf16(              \
              (wf)[s * 4 + j], xf[i], acc[i][j], 0, 0, 0);                  \
    }                                                                       \
  } while (0)

__device__ __forceinline__ void gemm_core(const bf16* __restrict__ A,       // [M][2048]
                                          const bf16* __restrict__ wpanel,  // packed n-panel
                                          int m0,
                                          bf16* sA,                         // 2*8192 elems
                                          f32x4 acc[4][4]) {
  const int tid = threadIdx.x;
  const int wave = tid >> 6, lane = tid & 63;
  const int quad = lane >> 4, l16 = lane & 15;
  const int rw = (wave >> 1) * 64;

  const f32x4 zero = {0.f, 0.f, 0.f, 0.f};
#pragma unroll
  for (int i = 0; i < 4; ++i)
#pragma unroll
    for (int j = 0; j < 4; ++j) acc[i][j] = zero;

  const int row = tid & 127;
  // aptr covers staging call r via +r*16 (kb = 2r + (tid>>7)); baked into macro via chunk math:
  const bf16* aptr = A + (size_t)(m0 + row) * DMODEL + (tid >> 7) * 8;
  const bf16* wb = wpanel + (size_t)(wave & 1) * 4 * 512 + (size_t)lane * 8;

  bf16* buf0 = sA;
  bf16* buf1 = sA + 8192;

  bf16x8 wfE[8], wfO[8];

  // prologue: stage A(0) -> buf0, load B(0) -> wfE
  {
    const bf16* _src = aptr;
    load_lds16(_src,      buf0 + tid * 8);
    load_lds16(_src + 16, buf0 + (256 + tid) * 8);
    load_lds16(_src + 32, buf0 + (512 + tid) * 8);
    load_lds16(_src + 48, buf0 + (768 + tid) * 8);
  }
  GEMM_LOAD_B(wfE, 0);

  for (int kt = 0; kt < 32; kt += 2) {
    __syncthreads();                 // A(kt) staged in buf0
    // prefetch A(kt+1) -> buf1, B(kt+1) -> wfO   (kt+1 <= 31 always)
    GEMM_STAGE_A(buf1, kt + 1);
    GEMM_LOAD_B(wfO, kt + 1);
    GEMM_COMPUTE(buf0, wfE);

    __syncthreads();                 // A(kt+1) staged in buf1
    if (kt + 2 < 32) {
      GEMM_STAGE_A(buf0, kt + 2);
      GEMM_LOAD_B(wfE, kt + 2);
    }
    GEMM_COMPUTE(buf1, wfO);
  }
}

// A-staging correctness note: GEMM_STAGE_A call r-th load handles chunk
// c = r*256+tid -> kb = 2r+(tid>>7), row = tid&127; src k-offset = kb*8 =
// r*16 + (tid>>7)*8, matching aptr + kt*64 + r*16. ds_read sub-chunk s uses
// chunk (4s+quad)*128 + row -> k = s*32 + quad*8. Verified algebraically.

// QKV projection: Q,K -> chunked [bh][kc][s][8]; V -> row-major [bh][s][d]
// grid: x = m-tile (64), y = n-tile (48)
__global__ __launch_bounds__(256) void gemm_qkv(
    const bf16* __restrict__ A, const bf16* __restrict__ wpack,
    const float* __restrict__ bq, const float* __restrict__ bk, const float* __restrict__ bv,
    bf16* __restrict__ qc, bf16* __restrict__ kc_, bf16* __restrict__ vb) {
  __shared__ alignas(16) bf16 sA[2 * 8192];   // 32KB
  const int m0 = blockIdx.x * 128, n0 = blockIdx.y * 128;
  f32x4 acc[4][4];
  gemm_core(A, wpack + (size_t)blockIdx.y * KT32 * TILE_ELEMS, m0, sA, acc);

  const int tid = threadIdx.x, wave = tid >> 6, lane = tid & 63;
  const int quad = lane >> 4, l16 = lane & 15;
  const int rw = (wave >> 1) * 64, cw = (wave & 1) * 64;

  const float* bias; bf16* dst; int chunked;
  if (n0 < 2048)      { bias = bq; dst = qc;  chunked = 1; }
  else if (n0 < 4096) { bias = bk; dst = kc_; chunked = 1; }
  else                { bias = bv; dst = vb;  chunked = 0; }
  const int nb = n0 & 2047;
#pragma unroll
  for (int i = 0; i < 4; ++i) {
    int m = m0 + rw + i * 16 + l16;
    int b = m >> 11, s = m & 2047;
#pragma unroll
    for (int j = 0; j < 4; ++j) {
      int n = nb + cw + j * 16 + quad * 4;
      int h = n >> 7, d = n & 127;
      bf16x4 v;
#pragma unroll
      for (int r = 0; r < 4; ++r) v[r] = (bf16)(acc[i][j][r] + bias[n + r]);
      size_t bhoff = (size_t)(b * NHEAD + h) * BH_STRIDE;
      if (chunked)
        *(bf16x4*)(dst + bhoff + (size_t)(d >> 3) * (S_TOK * 8) + (size_t)s * 8 + (d & 7)) = v;
      else
        *(bf16x4*)(dst + bhoff + (size_t)s * HDIM + d) = v;
    }
  }
}

// output projection: fp32 out, fused bias.  grid: x = m-tile (64), y = n-tile (16)
__global__ __launch_bounds__(256) void gemm_out(
    const bf16* __restrict__ A, const bf16* __restrict__ wpack,
    const float* __restrict__ bo, float* __restrict__ out) {
  __shared__ alignas(16) bf16 sA[2 * 8192];
  const int m0 = blockIdx.x * 128, n0 = blockIdx.y * 128;
  f32x4 acc[4][4];
  gemm_core(A, wpack + (size_t)blockIdx.y * KT32 * TILE_ELEMS, m0, sA, acc);

  const int tid = threadIdx.x, wave = tid >> 6, lane = tid & 63;
  const int quad = lane >> 4, l16 = lane & 15;
  const int rw = (wave >> 1) * 64, cw = (wave & 1) * 64;
#pragma unroll
  for (int i = 0; i < 4; ++i) {
    int m = m0 + rw + i * 16 + l16;
#pragma unroll
    for (int j = 0; j < 4; ++j) {
      int n = n0 + cw + j * 16 + quad * 4;
      f32x4 v = acc[i][j];
#pragma unroll
      for (int r = 0; r < 4; ++r) v[r] += bo[n + r];
      *(f32x4*)(out + (size_t)m * DMODEL + n) = v;
    }
  }
}

// ---------------- flash attention ----------------
__global__ __launch_bounds__(256) void flash_kernel(
    const bf16* __restrict__ qc, const bf16* __restrict__ kcg,
    const bf16* __restrict__ vcg, bf16* __restrict__ ob) {
  __shared__ alignas(16) bf16 sK[16 * 64 * 8];   // 16KB
  __shared__ alignas(16) bf16 sV[8 * 128 * 8];   // 16KB
  __shared__ alignas(16) bf16 sQ[16 * 64 * 8];   // staged Q; reused as sP

  const int tid = threadIdx.x, wave = tid >> 6, lane = tid & 63;
  const int quad = lane >> 4, l16 = lane & 15;
  const int bh = blockIdx.y;
  const int q0 = blockIdx.x * 64;

  const bf16* Qg = qc  + (size_t)bh * BH_STRIDE;
  const bf16* Kg = kcg + (size_t)bh * BH_STRIDE;
  const bf16* Vg = vcg + (size_t)bh * BH_STRIDE;

#pragma unroll
  for (int r = 0; r < 4; ++r) {
    int c = r * 256 + tid;
    load_lds16(Qg + (size_t)(c >> 6) * (S_TOK * 8) + (size_t)(q0 + (c & 63)) * 8,
               sQ + (size_t)c * 8);
  }
  __syncthreads();

  bf16x8 qf[4];
#pragma unroll
  for (int ks = 0; ks < 4; ++ks)
    qf[ks] = *(const bf16x8*)(sQ + ((size_t)(ks * 4 + quad) * 64 + wave * 16 + l16) * 8);

  bf16* sPw = sQ + wave * 1024;

  const float SLOG = 0.08838834764831845f * 1.4426950408889634f;
  float m_i = -1e30f, l_i = 0.f;
  f32x4 o[8];
  const f32x4 zero = {0.f, 0.f, 0.f, 0.f};
#pragma unroll
  for (int dt = 0; dt < 8; ++dt) o[dt] = zero;

  for (int kv = 0; kv < S_TOK; kv += 64) {
    __syncthreads();
#pragma unroll
    for (int r = 0; r < 4; ++r) {
      int c = r * 256 + tid;
      load_lds16(Kg + (size_t)(c >> 6) * (S_TOK * 8) + (size_t)(kv + (c & 63)) * 8,
                 sK + (size_t)c * 8);
    }
#pragma unroll
    for (int r = 0; r < 4; ++r) {
      int c = r * 256 + tid;
      load_lds16(Vg + (size_t)((kv >> 3) + (c >> 7)) * (HDIM * 8) + (size_t)(c & 127) * 8,
                 sV + (size_t)c * 8);
    }
    __syncthreads();

    f32x4 sc[4];
#pragma unroll
    for (int i = 0; i < 4; ++i) {
      sc[i] = zero;
#pragma unroll
      for (int ks = 0; ks < 4; ++ks) {
        bf16x8 kf = *(const bf16x8*)(sK + ((size_t)(ks * 4 + quad) * 64 + i * 16 + l16) * 8);
        sc[i] = __builtin_amdgcn_mfma_f32_16x16x32_bf16(kf, qf[ks], sc[i], 0, 0, 0);
      }
    }

    float mx = m_i;
#pragma unroll
    for (int i = 0; i < 4; ++i)
#pragma unroll
      for (int r = 0; r < 4; ++r) {
        float t = sc[i][r] * SLOG;
        sc[i][r] = t;
        mx = fmaxf(mx, t);
      }
    mx = fmaxf(mx, __shfl_xor(mx, 16));
    mx = fmaxf(mx, __shfl_xor(mx, 32));
    float alpha = __builtin_amdgcn_exp2f(m_i - mx);
    m_i = mx;

    float rs = 0.f;
    bf16x4 pv[4];
#pragma unroll
    for (int i = 0; i < 4; ++i)
#pragma unroll
      for (int r = 0; r < 4; ++r) {
        float pe = __builtin_amdgcn_exp2f(sc[i][r] - mx);
        rs += pe;
        pv[i][r] = (bf16)pe;
      }
    rs += __shfl_xor(rs, 16);
    rs += __shfl_xor(rs, 32);
    l_i = l_i * alpha + rs;

#pragma unroll
    for (int i = 0; i < 4; ++i)
      *(bf16x4*)(sPw + (size_t)(i * 2 + (quad >> 1)) * 128 + l16 * 8 + (quad & 1) * 4) = pv[i];

#pragma unroll
    for (int dt = 0; dt < 8; ++dt) o[dt] = o[dt] * alpha;

    bf16x8 pf0 = *(const bf16x8*)(sPw + (size_t)(quad * 16 + l16) * 8);
    bf16x8 pf1 = *(const bf16x8*)(sPw + (size_t)((4 + quad) * 16 + l16) * 8);
#pragma unroll
    for (int dt = 0; dt < 8; ++dt) {
      bf16x8 vf0 = *(const bf16x8*)(sV + ((size_t)quad * 128 + dt * 16 + l16) * 8);
      bf16x8 vf1 = *(const bf16x8*)(sV + ((size_t)(4 + quad) * 128 + dt * 16 + l16) * 8);
      o[dt] = __builtin_amdgcn_mfma_f32_16x16x32_bf16(vf0, pf0, o[dt], 0, 0, 0);
      o[dt] = __builtin_amdgcn_mfma_f32_16x16x32_bf16(vf1, pf1, o[dt], 0, 0, 0);
    }
  }

  float inv = 1.0f / l_i;
  int b = bh >> 4, h = bh & 15;
  int s = q0 + wave * 16 + l16;
  bf16* orow = ob + ((size_t)(b * S_TOK + s) * DMODEL + h * HDIM);
#pragma unroll
  for (int dt = 0; dt < 8; ++dt) {
    bf16x4 v;
#pragma unroll
    for (int r = 0; r < 4; ++r) v[r] = (bf16)(o[dt][r] * inv);
    *(bf16x4*)(orow + dt * 16 + quad * 4) = v;
  }
}

// ---------------- launch ----------------

extern "C" void kernel_launch(void* const* d_in, const int* in_sizes, int n_in,
                              void* d_out, int out_size, void* d_ws, size_t ws_size,
                              hipStream_t stream) {
  const float* x  = (const float*)d_in[0];
  const float* Wq = (const float*)d_in[2];
  const float* bq = (const float*)d_in[3];
  const float* Wk = (const float*)d_in[4];
  const float* bk = (const float*)d_in[5];
  const float* Wv = (const float*)d_in[6];
  const float* bv = (const float*)d_in[7];
  const float* Wo = (const float*)d_in[8];
  const float* bo = (const float*)d_in[9];
  float* out = (float*)d_out;

  const size_t M = 4 * (size_t)S_TOK;          // 8192
  const size_t SZ_TOK = M * DMODEL * 2;        // 33.5MB bf16 token-shaped buffer
  const size_t SZ_WMAT = (size_t)16 * KT32 * TILE_ELEMS * 2;

  char* p = (char*)d_ws;
  bf16* xb  = (bf16*)p; p += SZ_TOK;
  bf16* wp  = (bf16*)p; p += 3 * SZ_WMAT;
  bf16* wop = (bf16*)p; p += SZ_WMAT;
  bf16* qc  = (bf16*)p; p += SZ_TOK;
  bf16* kc  = (bf16*)p; p += SZ_TOK;
  bf16* vb  = (bf16*)p; p += SZ_TOK;
  bf16* vc  = (bf16*)p; p += SZ_TOK;
  bf16* ob  = xb;

  cvt_f32_bf16<<<dim3((unsigned)(M * DMODEL / 4 / 256)), 256, 0, stream>>>(x, xb);
  pack_w<<<dim3(KT32, 16), 256, 0, stream>>>(Wq, wp);
  pack_w<<<dim3(KT32, 16), 256, 0, stream>>>(Wk, wp + SZ_WMAT / 2);
  pack_w<<<dim3(KT32, 16), 256, 0, stream>>>(Wv, wp + SZ_WMAT);
  pack_w<<<dim3(KT32, 16), 256, 0, stream>>>(Wo, wop);

  gemm_qkv<<<dim3(64, 48), 256, 0, stream>>>(xb, wp, bq, bk, bv, qc, kc, vb);
  v_chunk<<<dim3(32, 64), 256, 0, stream>>>(vb, vc);
  flash_kernel<<<dim3(32, 64), 256, 0, stream>>>(qc, kc, vc, ob);
  gemm_out<<<dim3(64, 16), 256, 0, stream>>>(ob, wop, bo, out);
}

// Round 7
// 758.917 us; speedup vs baseline: 1.1594x; 1.1594x over previous
//
#include <hip/hip_runtime.h>

// Full MHA: x->QKV proj (bf16 MFMA GEMM) -> flash attention -> out proj.
// bf16 compute, fp32 accumulate.
// R7: gemm_qkv = pure flatmm: BOTH A and B pre-packed fragment-linear,
//     direct global->VGPR loads, NO LDS / NO barriers / NO stores in K-loop
//     (compiler pipelines with vmcnt; waves free-run). launch_bounds(256,4)
//     -> 4 waves/SIMD (unified VGPR+AGPR budget: 64 acc + 32 frag + addr).
//     R6 (BK=64, dual B-sets) regressed: 220 regs/wave -> 2 waves/SIMD.
//     gemm_out keeps R5 core (A=flash output, not packed).

typedef __bf16 bf16;
typedef __bf16 bf16x4 __attribute__((ext_vector_type(4)));
typedef __bf16 bf16x8 __attribute__((ext_vector_type(8)));
typedef float  f32x4  __attribute__((ext_vector_type(4)));

#define S_TOK 2048
#define DMODEL 2048
#define NHEAD 16
#define HDIM 128
#define BH_STRIDE ((size_t)S_TOK * HDIM)   // 262144 elems per (b,h)
#define KT32 (DMODEL / 32)                 // 64 32-k tiles per K
#define TILE_ELEMS 4096                    // 128(m|n) x 32k fragment-linear tile

__device__ __forceinline__ void load_lds16(const void* g, void* l) {
  __builtin_amdgcn_global_load_lds((const __attribute__((address_space(1))) void*)g,
                                   (__attribute__((address_space(3))) void*)l,
                                   16, 0, 0);
}

// ---------------- prep kernels ----------------

// Pack x fp32 [8192][2048] -> fragment-linear bf16 tiles:
// apack[(mt*64+kt)*4096 + f*512 + lane*8 + e]
//   = (bf16) x[mt*128 + f*16 + (lane&15)][kt*32 + (lane>>4)*8 + e]
// grid: x = kt (64), y = mt (64)
__global__ __launch_bounds__(256) void pack_a(const float* __restrict__ X,
                                              bf16* __restrict__ dst) {
  __shared__ bf16 lds[128 * 32];
  const int t = threadIdx.x;
  const int kt = blockIdx.x, mt = blockIdx.y;
  const int k0 = kt * 32, m0 = mt * 128;
  // coalesced read: 128 rows x 32k, 8 threads x float4 per row
#pragma unroll
  for (int p = 0; p < 4; ++p) {
    int r = p * 32 + (t >> 3);           // 0..127
    int c = (t & 7) * 4;                 // 0..28
    float4 v = *(const float4*)(X + (size_t)(m0 + r) * DMODEL + k0 + c);
    lds[r * 32 + c + 0] = (bf16)v.x;
    lds[r * 32 + c + 1] = (bf16)v.y;
    lds[r * 32 + c + 2] = (bf16)v.z;
    lds[r * 32 + c + 3] = (bf16)v.w;
  }
  __syncthreads();
  bf16* out = dst + ((size_t)mt * 64 + kt) * TILE_ELEMS;
#pragma unroll
  for (int u = 0; u < 2; ++u) {
    int c = t * 2 + u;                   // chunk 0..511
    int f = c >> 6, lane = c & 63;
    int l16 = lane & 15, q = lane >> 4;
    bf16x8 v;
#pragma unroll
    for (int e = 0; e < 8; ++e)
      v[e] = lds[(f * 16 + l16) * 32 + q * 8 + e];
    *(bf16x8*)(out + (size_t)c * 8) = v;
  }
}

// Pack W fp32 [K=2048][N=2048] row-major into fragment-linear bf16 tiles:
// dst[(nt*64 + kt)*4096 + i_g*512 + quad*128 + l16*8 + e]
//   = (bf16) W[kt*32 + quad*8 + e][nt*128 + i_g*16 + l16]
__global__ __launch_bounds__(256) void pack_w(const float* __restrict__ W,
                                              bf16* __restrict__ dst) {
  __shared__ bf16 lds[32 * 128];
  const int t = threadIdx.x;
  const int kt = blockIdx.x, nt = blockIdx.y;
  const int k0 = kt * 32, n0 = nt * 128;
#pragma unroll
  for (int p = 0; p < 4; ++p) {
    int kl = (t >> 5) + p * 8;
    int nl = (t & 31) * 4;
    float4 v = *(const float4*)(W + (size_t)(k0 + kl) * DMODEL + n0 + nl);
    lds[kl * 128 + nl + 0] = (bf16)v.x;
    lds[kl * 128 + nl + 1] = (bf16)v.y;
    lds[kl * 128 + nl + 2] = (bf16)v.z;
    lds[kl * 128 + nl + 3] = (bf16)v.w;
  }
  __syncthreads();
  bf16* out = dst + ((size_t)nt * KT32 + kt) * TILE_ELEMS;
#pragma unroll
  for (int u = 0; u < 2; ++u) {
    int c = t * 2 + u;
    int i_g = c >> 6, quad = (c >> 4) & 3, l16 = c & 15;
    bf16x8 v;
#pragma unroll
    for (int e = 0; e < 8; ++e)
      v[e] = lds[(quad * 8 + e) * 128 + i_g * 16 + l16];
    *(bf16x8*)(out + (size_t)c * 8) = v;
  }
}

// V reshuffle: vb[bh][s][d] -> vc[bh][s>>3][d][s&7]
__global__ __launch_bounds__(256) void v_chunk(const bf16* __restrict__ vb,
                                               bf16* __restrict__ vc) {
  __shared__ alignas(16) bf16 t[64 * 128];
  const int tid = threadIdx.x;
  const int s0 = blockIdx.x * 64;
  const size_t bhoff = (size_t)blockIdx.y * BH_STRIDE;
  const bf16* src = vb + bhoff + (size_t)s0 * HDIM;
#pragma unroll
  for (int r = 0; r < 4; ++r) {
    int c = r * 256 + tid;
    *(bf16x8*)(t + (size_t)c * 8) = *(const bf16x8*)(src + (size_t)(c >> 4) * HDIM + (c & 15) * 8);
  }
  __syncthreads();
  bf16* dst = vc + bhoff + (size_t)(s0 >> 3) * (HDIM * 8);
#pragma unroll
  for (int r = 0; r < 4; ++r) {
    int c = r * 256 + tid;
    int scl = c >> 7, d = c & 127;
    bf16x8 v;
#pragma unroll
    for (int e = 0; e < 8; ++e) v[e] = t[(size_t)(scl * 8 + e) * HDIM + d];
    *(bf16x8*)(dst + (size_t)scl * (HDIM * 8) + d * 8) = v;
  }
}

// ---------------- gemm_qkv: barrier-free flatmm ----------------
// A: fragment-packed activations (pack_a). B: fragment-packed weights (pack_w).
// Per iter per wave: 4 A-loads + 4 B-loads (dwordx4, direct to VGPR) + 16 MFMA.
// Q,K -> chunked [bh][kc][s][8]; V -> row-major [bh][s][d]
// grid: x = m-tile (64), y = n-tile (48)
__global__ __launch_bounds__(256, 4) void gemm_qkv(
    const bf16* __restrict__ apack, const bf16* __restrict__ wpack,
    const float* __restrict__ bq, const float* __restrict__ bk, const float* __restrict__ bv,
    bf16* __restrict__ qc, bf16* __restrict__ kc_, bf16* __restrict__ vb) {
  const int tid = threadIdx.x, wave = tid >> 6, lane = tid & 63;
  const int quad = lane >> 4, l16 = lane & 15;
  const int rw = (wave >> 1) * 64, cw = (wave & 1) * 64;
  const int m0 = blockIdx.x * 128, n0 = blockIdx.y * 128;

  const bf16* ap = apack + (size_t)blockIdx.x * 64 * TILE_ELEMS
                         + (size_t)(rw >> 4) * 512 + (size_t)lane * 8;
  const bf16* wb = wpack + (size_t)blockIdx.y * KT32 * TILE_ELEMS
                         + (size_t)(wave & 1) * 4 * 512 + (size_t)lane * 8;

  f32x4 acc[4][4];
  const f32x4 zero = {0.f, 0.f, 0.f, 0.f};
#pragma unroll
  for (int i = 0; i < 4; ++i)
#pragma unroll
    for (int j = 0; j < 4; ++j) acc[i][j] = zero;

#pragma unroll 2
  for (int kt = 0; kt < KT32; ++kt) {
    bf16x8 xf[4], wf[4];
#pragma unroll
    for (int i = 0; i < 4; ++i)
      xf[i] = *(const bf16x8*)(ap + (size_t)i * 512);
#pragma unroll
    for (int j = 0; j < 4; ++j)
      wf[j] = *(const bf16x8*)(wb + (size_t)j * 512);
    ap += TILE_ELEMS; wb += TILE_ELEMS;
#pragma unroll
    for (int i = 0; i < 4; ++i)
#pragma unroll
      for (int j = 0; j < 4; ++j)
        acc[i][j] = __builtin_amdgcn_mfma_f32_16x16x32_bf16(wf[j], xf[i], acc[i][j], 0, 0, 0);
  }

  const float* bias; bf16* dst; int chunked;
  if (n0 < 2048)      { bias = bq; dst = qc;  chunked = 1; }
  else if (n0 < 4096) { bias = bk; dst = kc_; chunked = 1; }
  else                { bias = bv; dst = vb;  chunked = 0; }
  const int nb = n0 & 2047;
#pragma unroll
  for (int i = 0; i < 4; ++i) {
    int m = m0 + rw + i * 16 + l16;
    int b = m >> 11, s = m & 2047;
#pragma unroll
    for (int j = 0; j < 4; ++j) {
      int n = nb + cw + j * 16 + quad * 4;
      int h = n >> 7, d = n & 127;
      bf16x4 v;
#pragma unroll
      for (int r = 0; r < 4; ++r) v[r] = (bf16)(acc[i][j][r] + bias[n + r]);
      size_t bhoff = (size_t)(b * NHEAD + h) * BH_STRIDE;
      if (chunked)
        *(bf16x4*)(dst + bhoff + (size_t)(d >> 3) * (S_TOK * 8) + (size_t)s * 8 + (d & 7)) = v;
      else
        *(bf16x4*)(dst + bhoff + (size_t)s * HDIM + d) = v;
    }
  }
}

// ---------------- gemm_out: R5 core (A row-major via LDS dbuf, B direct) ----------------
__device__ __forceinline__ void gemm_core_lds(const bf16* __restrict__ A,       // [M][2048]
                                              const bf16* __restrict__ wpanel,  // packed n-panel
                                              int m0, bf16* sA, f32x4 acc[4][4]) {
  const int tid = threadIdx.x;
  const int wave = tid >> 6, lane = tid & 63;
  const int quad = lane >> 4, l16 = lane & 15;
  const int rw = (wave >> 1) * 64;

  const f32x4 zero = {0.f, 0.f, 0.f, 0.f};
#pragma unroll
  for (int i = 0; i < 4; ++i)
#pragma unroll
    for (int j = 0; j < 4; ++j) acc[i][j] = zero;

  const int kb0 = tid >> 7;
  const int row = tid & 127;
  const bf16* a0 = A + (size_t)(m0 + row) * DMODEL + kb0 * 8;
  const bf16* a1 = a0 + 16;
  const bf16* wb = wpanel + (size_t)(wave & 1) * 4 * 512 + (size_t)lane * 8;

  load_lds16(a0, sA + tid * 8); load_lds16(a1, sA + (256 + tid) * 8);
  a0 += 32; a1 += 32;
  bf16x8 wfc[4], wfn[4];
#pragma unroll
  for (int j = 0; j < 4; ++j)
    wfc[j] = *(const bf16x8*)(wb + (size_t)j * 512);

#pragma unroll 2
  for (int kt = 0; kt < KT32; ++kt) {
    __syncthreads();
    const int cur = kt & 1, nxt = cur ^ 1;
    if (kt + 1 < KT32) {
      load_lds16(a0, sA + (nxt * 512 + tid) * 8);
      load_lds16(a1, sA + (nxt * 512 + 256 + tid) * 8);
      a0 += 32; a1 += 32;
      const bf16* wn = wb + (size_t)(kt + 1) * TILE_ELEMS;
#pragma unroll
      for (int j = 0; j < 4; ++j)
        wfn[j] = *(const bf16x8*)(wn + (size_t)j * 512);
    }
    const bf16* sAc = sA + cur * 4096;
    bf16x8 xf[4];
#pragma unroll
    for (int i = 0; i < 4; ++i)
      xf[i] = *(const bf16x8*)(sAc + ((size_t)quad * 128 + rw + i * 16 + l16) * 8);
#pragma unroll
    for (int i = 0; i < 4; ++i)
#pragma unroll
      for (int j = 0; j < 4; ++j)
        acc[i][j] = __builtin_amdgcn_mfma_f32_16x16x32_bf16(wfc[j], xf[i], acc[i][j], 0, 0, 0);
#pragma unroll
    for (int j = 0; j < 4; ++j) wfc[j] = wfn[j];
  }
}

// output projection: fp32 out, fused bias.  grid: x = m-tile (64), y = n-tile (16)
__global__ __launch_bounds__(256) void gemm_out(
    const bf16* __restrict__ A, const bf16* __restrict__ wpack,
    const float* __restrict__ bo, float* __restrict__ out) {
  __shared__ alignas(16) bf16 sA[2 * 4096];
  const int m0 = blockIdx.x * 128, n0 = blockIdx.y * 128;
  f32x4 acc[4][4];
  gemm_core_lds(A, wpack + (size_t)blockIdx.y * KT32 * TILE_ELEMS, m0, sA, acc);

  const int tid = threadIdx.x, wave = tid >> 6, lane = tid & 63;
  const int quad = lane >> 4, l16 = lane & 15;
  const int rw = (wave >> 1) * 64, cw = (wave & 1) * 64;
#pragma unroll
  for (int i = 0; i < 4; ++i) {
    int m = m0 + rw + i * 16 + l16;
#pragma unroll
    for (int j = 0; j < 4; ++j) {
      int n = n0 + cw + j * 16 + quad * 4;
      f32x4 v = acc[i][j];
#pragma unroll
      for (int r = 0; r < 4; ++r) v[r] += bo[n + r];
      *(f32x4*)(out + (size_t)m * DMODEL + n) = v;
    }
  }
}

// ---------------- flash attention ----------------
__global__ __launch_bounds__(256) void flash_kernel(
    const bf16* __restrict__ qc, const bf16* __restrict__ kcg,
    const bf16* __restrict__ vcg, bf16* __restrict__ ob) {
  __shared__ alignas(16) bf16 sK[16 * 64 * 8];   // 16KB
  __shared__ alignas(16) bf16 sV[8 * 128 * 8];   // 16KB
  __shared__ alignas(16) bf16 sQ[16 * 64 * 8];   // staged Q; reused as sP

  const int tid = threadIdx.x, wave = tid >> 6, lane = tid & 63;
  const int quad = lane >> 4, l16 = lane & 15;
  const int bh = blockIdx.y;
  const int q0 = blockIdx.x * 64;

  const bf16* Qg = qc  + (size_t)bh * BH_STRIDE;
  const bf16* Kg = kcg + (size_t)bh * BH_STRIDE;
  const bf16* Vg = vcg + (size_t)bh * BH_STRIDE;

#pragma unroll
  for (int r = 0; r < 4; ++r) {
    int c = r * 256 + tid;
    load_lds16(Qg + (size_t)(c >> 6) * (S_TOK * 8) + (size_t)(q0 + (c & 63)) * 8,
               sQ + (size_t)c * 8);
  }
  __syncthreads();

  bf16x8 qf[4];
#pragma unroll
  for (int ks = 0; ks < 4; ++ks)
    qf[ks] = *(const bf16x8*)(sQ + ((size_t)(ks * 4 + quad) * 64 + wave * 16 + l16) * 8);

  bf16* sPw = sQ + wave * 1024;

  const float SLOG = 0.08838834764831845f * 1.4426950408889634f;
  float m_i = -1e30f, l_i = 0.f;
  f32x4 o[8];
  const f32x4 zero = {0.f, 0.f, 0.f, 0.f};
#pragma unroll
  for (int dt = 0; dt < 8; ++dt) o[dt] = zero;

  for (int kv = 0; kv < S_TOK; kv += 64) {
    __syncthreads();
#pragma unroll
    for (int r = 0; r < 4; ++r) {
      int c = r * 256 + tid;
      load_lds16(Kg + (size_t)(c >> 6) * (S_TOK * 8) + (size_t)(kv + (c & 63)) * 8,
                 sK + (size_t)c * 8);
    }
#pragma unroll
    for (int r = 0; r < 4; ++r) {
      int c = r * 256 + tid;
      load_lds16(Vg + (size_t)((kv >> 3) + (c >> 7)) * (HDIM * 8) + (size_t)(c & 127) * 8,
                 sV + (size_t)c * 8);
    }
    __syncthreads();

    f32x4 sc[4];
#pragma unroll
    for (int i = 0; i < 4; ++i) {
      sc[i] = zero;
#pragma unroll
      for (int ks = 0; ks < 4; ++ks) {
        bf16x8 kf = *(const bf16x8*)(sK + ((size_t)(ks * 4 + quad) * 64 + i * 16 + l16) * 8);
        sc[i] = __builtin_amdgcn_mfma_f32_16x16x32_bf16(kf, qf[ks], sc[i], 0, 0, 0);
      }
    }

    float mx = m_i;
#pragma unroll
    for (int i = 0; i < 4; ++i)
#pragma unroll
      for (int r = 0; r < 4; ++r) {
        float t = sc[i][r] * SLOG;
        sc[i][r] = t;
        mx = fmaxf(mx, t);
      }
    mx = fmaxf(mx, __shfl_xor(mx, 16));
    mx = fmaxf(mx, __shfl_xor(mx, 32));
    float alpha = __builtin_amdgcn_exp2f(m_i - mx);
    m_i = mx;

    float rs = 0.f;
    bf16x4 pv[4];
#pragma unroll
    for (int i = 0; i < 4; ++i)
#pragma unroll
      for (int r = 0; r < 4; ++r) {
        float pe = __builtin_amdgcn_exp2f(sc[i][r] - mx);
        rs += pe;
        pv[i][r] = (bf16)pe;
      }
    rs += __shfl_xor(rs, 16);
    rs += __shfl_xor(rs, 32);
    l_i = l_i * alpha + rs;

#pragma unroll
    for (int i = 0; i < 4; ++i)
      *(bf16x4*)(sPw + (size_t)(i * 2 + (quad >> 1)) * 128 + l16 * 8 + (quad & 1) * 4) = pv[i];

#pragma unroll
    for (int dt = 0; dt < 8; ++dt) o[dt] = o[dt] * alpha;

    bf16x8 pf0 = *(const bf16x8*)(sPw + (size_t)(quad * 16 + l16) * 8);
    bf16x8 pf1 = *(const bf16x8*)(sPw + (size_t)((4 + quad) * 16 + l16) * 8);
#pragma unroll
    for (int dt = 0; dt < 8; ++dt) {
      bf16x8 vf0 = *(const bf16x8*)(sV + ((size_t)quad * 128 + dt * 16 + l16) * 8);
      bf16x8 vf1 = *(const bf16x8*)(sV + ((size_t)(4 + quad) * 128 + dt * 16 + l16) * 8);
      o[dt] = __builtin_amdgcn_mfma_f32_16x16x32_bf16(vf0, pf0, o[dt], 0, 0, 0);
      o[dt] = __builtin_amdgcn_mfma_f32_16x16x32_bf16(vf1, pf1, o[dt], 0, 0, 0);
    }
  }

  float inv = 1.0f / l_i;
  int b = bh >> 4, h = bh & 15;
  int s = q0 + wave * 16 + l16;
  bf16* orow = ob + ((size_t)(b * S_TOK + s) * DMODEL + h * HDIM);
#pragma unroll
  for (int dt = 0; dt < 8; ++dt) {
    bf16x4 v;
#pragma unroll
    for (int r = 0; r < 4; ++r) v[r] = (bf16)(o[dt][r] * inv);
    *(bf16x4*)(orow + dt * 16 + quad * 4) = v;
  }
}

// ---------------- launch ----------------

extern "C" void kernel_launch(void* const* d_in, const int* in_sizes, int n_in,
                              void* d_out, int out_size, void* d_ws, size_t ws_size,
                              hipStream_t stream) {
  const float* x  = (const float*)d_in[0];
  const float* Wq = (const float*)d_in[2];
  const float* bq = (const float*)d_in[3];
  const float* Wk = (const float*)d_in[4];
  const float* bk = (const float*)d_in[5];
  const float* Wv = (const float*)d_in[6];
  const float* bv = (const float*)d_in[7];
  const float* Wo = (const float*)d_in[8];
  const float* bo = (const float*)d_in[9];
  float* out = (float*)d_out;

  const size_t M = 4 * (size_t)S_TOK;          // 8192
  const size_t SZ_TOK = M * DMODEL * 2;        // 33.5MB bf16 token-shaped buffer
  const size_t SZ_WMAT = (size_t)16 * KT32 * TILE_ELEMS * 2;

  char* p = (char*)d_ws;
  bf16* ap  = (bf16*)p; p += SZ_TOK;           // packed activations; reused as ob
  bf16* wp  = (bf16*)p; p += 3 * SZ_WMAT;      // packed Wq|Wk|Wv
  bf16* wop = (bf16*)p; p += SZ_WMAT;          // packed Wo
  bf16* qc  = (bf16*)p; p += SZ_TOK;
  bf16* kc  = (bf16*)p; p += SZ_TOK;
  bf16* vb  = (bf16*)p; p += SZ_TOK;
  bf16* vc  = (bf16*)p; p += SZ_TOK;
  bf16* ob  = ap;   // apack dead after gemm_qkv; flash writes ob here

  pack_a<<<dim3(64, 64), 256, 0, stream>>>(x, ap);
  pack_w<<<dim3(KT32, 16), 256, 0, stream>>>(Wq, wp);
  pack_w<<<dim3(KT32, 16), 256, 0, stream>>>(Wk, wp + SZ_WMAT / 2);
  pack_w<<<dim3(KT32, 16), 256, 0, stream>>>(Wv, wp + SZ_WMAT);
  pack_w<<<dim3(KT32, 16), 256, 0, stream>>>(Wo, wop);

  gemm_qkv<<<dim3(64, 48), 256, 0, stream>>>(ap, wp, bq, bk, bv, qc, kc, vb);
  v_chunk<<<dim3(32, 64), 256, 0, stream>>>(vb, vc);
  flash_kernel<<<dim3(32, 64), 256, 0, stream>>>(qc, kc, vc, ob);
  gemm_out<<<dim3(64, 16), 256, 0, stream>>>(ob, wop, bo, out);
}